// Round 11
// baseline (4071.996 us; speedup 1.0000x reference)
//
#include <hip/hip_runtime.h>
#include <cstdint>
#include <cstddef>

// ViT-B/16 + token pruning. Round 11: 128x256 tile (wgemm_k) for qkv/fc1 with
// the PROVEN ring-3 counted-vmcnt schedule (R9/R10 mgemm structure, unchanged)
// - 32 MFMA per wave per barrier (2x amortization of the fixed per-iter stall)
// - 85 FLOP per staged byte (vs 64 at 128^2)
// proj/fc2/patch/head remain on the 128^2 mgemm kernel.

#define NTOK 197
#define NB 64
#define NHEAD 12
#define SL 99

typedef __attribute__((ext_vector_type(8))) _Float16 half8;
typedef __attribute__((ext_vector_type(4))) float f32x4;
typedef __attribute__((ext_vector_type(4))) unsigned short us4;

#define DEV static __device__ __forceinline__

DEV unsigned short f2h(float f) {
    union { _Float16 h; unsigned short u; } v;
    v.h = (_Float16)f;
    return v.u;
}
DEV float h2f(unsigned short u) {
    union { _Float16 h; unsigned short u; } v;
    v.u = u;
    return (float)v.h;
}

DEV void gload16(const void* g, void* l) {
    __builtin_amdgcn_global_load_lds((const __attribute__((address_space(1))) unsigned int*)g,
                                     (__attribute__((address_space(3))) unsigned int*)l, 16, 0, 0);
}

// ---------------------------------------------------------------- weight conversion (4 layers / launch)
__global__ __launch_bounds__(256) void cvt_layer4_k(const float* __restrict__ qw,
                                                    const float* __restrict__ pw,
                                                    const float* __restrict__ f1,
                                                    const float* __restrict__ f2,
                                                    int i0,
                                                    unsigned short* __restrict__ dst)
{
    int l = blockIdx.x / 6912;
    int b2 = blockIdx.x % 6912;
    int li = i0 + l;
    size_t t = (size_t)b2 * 256 + threadIdx.x;
    size_t e = t * 4;
    const float* src; size_t loc;
    if (e < 1769472)      { src = qw + (size_t)li * 1769472; loc = e; }
    else if (e < 2359296) { src = pw + (size_t)li * 589824;  loc = e - 1769472; }
    else if (e < 4718592) { src = f1 + (size_t)li * 2359296; loc = e - 2359296; }
    else                  { src = f2 + (size_t)li * 2359296; loc = e - 4718592; }
    float4 v = *(const float4*)(src + loc);
    us4 hi; hi.x = f2h(v.x); hi.y = f2h(v.y); hi.z = f2h(v.z); hi.w = f2h(v.w);
    *(us4*)(dst + (size_t)l * 7077888 + e) = hi;
}

__global__ __launch_bounds__(256) void cvt_simple_k(const float* __restrict__ src,
                                                    unsigned short* __restrict__ dh, int n4)
{
    int t = blockIdx.x * 256 + threadIdx.x;
    if (t >= n4) return;
    size_t e = (size_t)t * 4;
    float4 v = *(const float4*)(src + e);
    us4 hi; hi.x = f2h(v.x); hi.y = f2h(v.y); hi.z = f2h(v.z); hi.w = f2h(v.w);
    *(us4*)(dh + e) = hi;
}

// ---------------------------------------------------------------- patch extract
__global__ __launch_bounds__(256) void patch_extract2_k(const float* __restrict__ img,
                                                        unsigned short* __restrict__ ph)
{
    int pi = blockIdx.x, b = blockIdx.y;
    int gy = pi / 14, gx = pi % 14;
    size_t obase = ((size_t)b * 196 + pi) * 768;
    for (int f = threadIdx.x; f < 768; f += 256) {
        int c = f >> 8, py = (f >> 4) & 15, px = f & 15;
        float v = img[(((size_t)b * 3 + c) * 224 + gy * 16 + py) * 224 + gx * 16 + px];
        ph[obase + f] = f2h(v);
    }
}

__global__ __launch_bounds__(256) void assemble_k(const unsigned short* __restrict__ emb,
                                                  const float* __restrict__ cls,
                                                  const float* __restrict__ pos,
                                                  unsigned short* __restrict__ x)
{
    int s = blockIdx.x, b = blockIdx.y;
    size_t xo = ((size_t)b * NTOK + s) * 768;
    for (int d = threadIdx.x; d < 768; d += 256) {
        float v = (s == 0) ? cls[d] : h2f(emb[((size_t)b * 196 + (s - 1)) * 768 + d]);
        x[xo + d] = f2h(v + pos[(size_t)s * 768 + d]);
    }
}

// ---------------------------------------------------------------- layernorm fp16 -> fp16
__global__ __launch_bounds__(256) void ln2_k(const unsigned short* __restrict__ in,
                                             unsigned short* __restrict__ outh,
                                             const float* __restrict__ g,
                                             const float* __restrict__ bt, size_t ldin)
{
    const unsigned short* xr = in + (size_t)blockIdx.x * ldin;
    size_t ob = (size_t)blockIdx.x * 768;
    int t = threadIdx.x;
    float v0 = h2f(xr[t]), v1 = h2f(xr[t + 256]), v2 = h2f(xr[t + 512]);
    float s = v0 + v1 + v2;
#pragma unroll
    for (int o = 32; o; o >>= 1) s += __shfl_xor(s, o);
    __shared__ float r1[4], r2[4];
    int wv = t >> 6, ln = t & 63;
    if (ln == 0) r1[wv] = s;
    __syncthreads();
    float mean = (r1[0] + r1[1] + r1[2] + r1[3]) * (1.f / 768.f);
    float d0 = v0 - mean, d1 = v1 - mean, d2 = v2 - mean;
    float ss = d0 * d0 + d1 * d1 + d2 * d2;
#pragma unroll
    for (int o = 32; o; o >>= 1) ss += __shfl_xor(ss, o);
    if (ln == 0) r2[wv] = ss;
    __syncthreads();
    float inv = rsqrtf((r2[0] + r2[1] + r2[2] + r2[3]) * (1.f / 768.f) + 1e-6f);
    outh[ob + t]       = f2h(d0 * inv * g[t]       + bt[t]);
    outh[ob + t + 256] = f2h(d1 * inv * g[t + 256] + bt[t + 256]);
    outh[ob + t + 512] = f2h(d2 * inv * g[t + 512] + bt[t + 512]);
}

// ---------------------------------------------------------------- 128x256 fp16 GEMM, ring-3 pipeline
// A[M,K], W[N,K] fp16. Wave tile 64x128 (acc 4x8). Chunked-XCD rows-fastest.
// Same schedule as mgemm_k: counted vmcnt(6), ONE barrier/iter, no fences.
// EPI: 0 none, 1 GELU. OS must be 1 (fp16 out). Dynamic LDS 72KB (3 x 24KB).
template<int EPI>
__global__ __launch_bounds__(256, 2) void wgemm_k(const unsigned short* __restrict__ Ah,
                                                  const unsigned short* __restrict__ Wh,
                                                  const float* __restrict__ bias,
                                                  unsigned short* __restrict__ Chi,
                                                  int M, int N, int K, int nR, int nC, int nRloc)
{
    extern __shared__ unsigned short lds[];   // 3 slots x (A 4096 + B 8192 shorts) = 72 KiB

    int rt, ct;
    {
        int bid = blockIdx.x;
        int xcd = bid & 7, u = bid >> 3;
        int rl = u % nRloc, c = u / nRloc;
        rt = xcd * nRloc + rl; ct = c;
        if (rt >= nR) return;
    }
    const int row0 = rt << 7, col0 = ct << 8;
    const int tid = threadIdx.x;
    const int w = tid >> 6, lane = tid & 63;
    const int wr = w >> 1, wc = w & 1;           // wave tile: rows wr*64, cols wc*128
    const int srow = lane >> 2;
    const int schunk = ((lane & 3) ^ ((srow >> 1) & 3)) << 3;
    const int fr = lane & 15, fq = lane >> 4;
    const int rchunk = (fq ^ ((fr >> 1) & 3)) << 3;

    f32x4 acc[4][8];
#pragma unroll
    for (int m = 0; m < 4; m++)
#pragma unroll
        for (int n = 0; n < 8; n++) acc[m][n] = (f32x4)0.f;

    const int nk = K >> 5;

    auto stage = [&](int t, int slot) {
        const int k0 = t << 5;
        unsigned short* Ad = lds + slot * 12288;
        unsigned short* Bd = Ad + 4096;
#pragma unroll
        for (int i = 0; i < 2; i++) {
            int r = i * 64 + w * 16 + srow;
            int ga = row0 + r; if (ga > M - 1) ga = M - 1;
            gload16(Ah + (size_t)ga * K + k0 + schunk, Ad + i * 2048 + w * 512);
        }
#pragma unroll
        for (int i = 0; i < 4; i++) {
            int r = i * 64 + w * 16 + srow;
            int gb = col0 + r; if (gb > N - 1) gb = N - 1;
            gload16(Wh + (size_t)gb * K + k0 + schunk, Bd + i * 2048 + w * 512);
        }
    };

    stage(0, 0);
    stage(1, 1);
    int slot = 0, slot2 = 2;
    for (int t = 0; t < nk; ++t) {
        if (t + 1 < nk) asm volatile("s_waitcnt vmcnt(6)" ::: "memory");
        else            asm volatile("s_waitcnt vmcnt(0)" ::: "memory");
        __builtin_amdgcn_s_barrier();
        if (t + 2 < nk) stage(t + 2, slot2);
        const unsigned short* Ab = lds + slot * 12288;
        const unsigned short* Bb = Ab + 4096;
        half8 a[4], bb[8];
#pragma unroll
        for (int m = 0; m < 4; m++)
            a[m] = *(const half8*)(Ab + (wr * 64 + m * 16 + fr) * 32 + rchunk);
#pragma unroll
        for (int n = 0; n < 8; n++)
            bb[n] = *(const half8*)(Bb + (wc * 128 + n * 16 + fr) * 32 + rchunk);
#pragma unroll
        for (int m = 0; m < 4; m++)
#pragma unroll
            for (int n = 0; n < 8; n++)
                acc[m][n] = __builtin_amdgcn_mfma_f32_16x16x32_f16(a[m], bb[n], acc[m][n], 0, 0, 0);
        slot = (slot == 2) ? 0 : slot + 1;
        slot2 = (slot2 == 2) ? 0 : slot2 + 1;
    }

#pragma unroll
    for (int m = 0; m < 4; m++) {
#pragma unroll
        for (int n = 0; n < 8; n++) {
            int col = col0 + wc * 128 + n * 16 + fr;
#pragma unroll
            for (int r = 0; r < 4; r++) {
                int row = row0 + wr * 64 + m * 16 + fq * 4 + r;
                if (row < M && col < N) {
                    float v = acc[m][n][r] + bias[col];
                    if (EPI == 1) v = 0.5f * v * (1.f + erff(v * 0.70710678118654752f));
                    Chi[(size_t)row * N + col] = f2h(v);
                }
            }
        }
    }
}

// ---------------------------------------------------------------- 128x128 fp16 GEMM, ring-3 (R9/R10)
// EPI: 0 none, 1 GELU, 2 +res(fp16). OS: 0 fp32 out, 1 fp16 out.
// MAP: 0 linear; 3 chunked rows-fastest; 4 chunked cols-fastest.
template<int EPI, int OS, int MAP>
__global__ __launch_bounds__(256) void mgemm_k(const unsigned short* __restrict__ Ah,
                                               const unsigned short* __restrict__ Wh,
                                               const float* __restrict__ bias,
                                               const unsigned short* __restrict__ res,
                                               unsigned short* __restrict__ Chi,
                                               float* __restrict__ Cf,
                                               int M, int N, int K, int nR, int nC, int nRloc)
{
    __shared__ unsigned short lds[3 * 8192];

    int rt, ct;
    {
        int bid = blockIdx.x;
        if (MAP == 0) { rt = bid % nR; ct = bid / nR; }
        else {
            int xcd = bid & 7, u = bid >> 3, rl, c;
            if (MAP == 3) { rl = u % nRloc; c = u / nRloc; }
            else          { c = u % nC;     rl = u / nC;   }
            rt = xcd * nRloc + rl; ct = c;
            if (rt >= nR) return;
        }
    }
    const int row0 = rt << 7, col0 = ct << 7;
    const int tid = threadIdx.x;
    const int w = tid >> 6, lane = tid & 63;
    const int wr = w >> 1, wc = w & 1;
    const int srow = lane >> 2;
    const int schunk = ((lane & 3) ^ ((srow >> 1) & 3)) << 3;
    const int fr = lane & 15, fq = lane >> 4;
    const int rchunk = (fq ^ ((fr >> 1) & 3)) << 3;

    f32x4 acc[4][4];
#pragma unroll
    for (int m = 0; m < 4; m++)
#pragma unroll
        for (int n = 0; n < 4; n++) acc[m][n] = (f32x4)0.f;

    const int nk = K >> 5;

    auto stage = [&](int t, int slot) {
        const int k0 = t << 5;
        unsigned short* Ad = lds + slot * 8192;
        unsigned short* Bd = Ad + 4096;
#pragma unroll
        for (int i = 0; i < 2; i++) {
            int r = i * 64 + w * 16 + srow;
            int ga = row0 + r; if (ga > M - 1) ga = M - 1;
            int gb = col0 + r; if (gb > N - 1) gb = N - 1;
            gload16(Ah + (size_t)ga * K + k0 + schunk, Ad + i * 2048 + w * 512);
            gload16(Wh + (size_t)gb * K + k0 + schunk, Bd + i * 2048 + w * 512);
        }
    };

    stage(0, 0);
    stage(1, 1);
    int slot = 0, slot2 = 2;
    for (int t = 0; t < nk; ++t) {
        if (t + 1 < nk) asm volatile("s_waitcnt vmcnt(4)" ::: "memory");
        else            asm volatile("s_waitcnt vmcnt(0)" ::: "memory");
        __builtin_amdgcn_s_barrier();
        if (t + 2 < nk) stage(t + 2, slot2);
        const unsigned short* Ab = lds + slot * 8192;
        const unsigned short* Bb = Ab + 4096;
        half8 a[4], bb[4];
#pragma unroll
        for (int m = 0; m < 4; m++)
            a[m] = *(const half8*)(Ab + (wr * 64 + m * 16 + fr) * 32 + rchunk);
#pragma unroll
        for (int n = 0; n < 4; n++)
            bb[n] = *(const half8*)(Bb + (wc * 64 + n * 16 + fr) * 32 + rchunk);
#pragma unroll
        for (int m = 0; m < 4; m++)
#pragma unroll
            for (int n = 0; n < 4; n++)
                acc[m][n] = __builtin_amdgcn_mfma_f32_16x16x32_f16(a[m], bb[n], acc[m][n], 0, 0, 0);
        slot = (slot == 2) ? 0 : slot + 1;
        slot2 = (slot2 == 2) ? 0 : slot2 + 1;
    }

#pragma unroll
    for (int m = 0; m < 4; m++) {
#pragma unroll
        for (int n = 0; n < 4; n++) {
            int col = col0 + wc * 64 + n * 16 + fr;
#pragma unroll
            for (int r = 0; r < 4; r++) {
                int row = row0 + wr * 64 + m * 16 + fq * 4 + r;
                if (row < M && col < N) {
                    float v = acc[m][n][r] + bias[col];
                    size_t o = (size_t)row * N + col;
                    if (EPI == 2) v += h2f(res[o]);
                    if (EPI == 1) v = 0.5f * v * (1.f + erff(v * 0.70710678118654752f));
                    if (OS == 0) Cf[o] = v;
                    else Chi[o] = f2h(v);
                }
            }
        }
    }
}

// ---------------------------------------------------------------- fused MFMA attention (fp16)
template<int S, int KT, int PVKT, int PSTR>
__global__ __launch_bounds__(256) void attn2_k(const unsigned short* __restrict__ qh,
                                               unsigned short* __restrict__ oh,
                                               const int* __restrict__ cntp)
{
    constexpr int PVK = PVKT * 32;
    constexpr int QT = (S + 15) / 16;
    extern __shared__ unsigned short sh[];
    unsigned short* VT = sh;
    unsigned short* PL = sh + 64 * PSTR;

    const int h = blockIdx.x, b = blockIdx.y;
    const int tid = threadIdx.x, w = tid >> 6, lane = tid & 63;
    const int nk = cntp ? cntp[b] : S;
    const size_t qbase = (size_t)b * S * 2304 + (size_t)h * 64;
    const int fr = lane & 15, fq = lane >> 4;

    for (int j0 = 0; j0 < S; j0 += 32) {
        int j = j0 + (tid >> 3);
        int d8 = (tid & 7) * 8;
        if (j < S) {
            size_t src = qbase + (size_t)j * 2304 + 1536 + d8;
            us4 v0 = *(const us4*)(qh + src);
            us4 v1 = *(const us4*)(qh + src + 4);
            VT[(d8 + 0) * PSTR + j] = v0.x; VT[(d8 + 1) * PSTR + j] = v0.y;
            VT[(d8 + 2) * PSTR + j] = v0.z; VT[(d8 + 3) * PSTR + j] = v0.w;
            VT[(d8 + 4) * PSTR + j] = v1.x; VT[(d8 + 5) * PSTR + j] = v1.y;
            VT[(d8 + 6) * PSTR + j] = v1.z; VT[(d8 + 7) * PSTR + j] = v1.w;
        }
    }
    for (int idx = tid; idx < 64 * (PVK - S); idx += 256) {
        int d = idx / (PVK - S), j = S + idx % (PVK - S);
        VT[d * PSTR + j] = 0;
    }
    {
        unsigned short* Pw = PL + w * 16 * PSTR;
        for (int idx = lane; idx < 16 * (PVK - 16 * KT); idx += 64) {
            int rr = idx / (PVK - 16 * KT), cc = 16 * KT + idx % (PVK - 16 * KT);
            Pw[rr * PSTR + cc] = 0;
        }
    }
    __syncthreads();

    for (int qt = w; qt < QT; qt += 4) {
        int qr = qt * 16 + fr; int qrc = qr < S ? qr : S - 1;
        const size_t qrow = qbase + (size_t)qrc * 2304;
        half8 qf0[2];
#pragma unroll
        for (int ks = 0; ks < 2; ks++)
            qf0[ks] = *(const half8*)(qh + qrow + ks * 32 + fq * 8);
        f32x4 sc[KT];
#pragma unroll
        for (int kt = 0; kt < KT; kt++) {
            int ky = kt * 16 + fr; int kyc = ky < S ? ky : S - 1;
            const size_t krow = qbase + (size_t)kyc * 2304 + 768;
            f32x4 acc = (f32x4)0.f;
#pragma unroll
            for (int ks = 0; ks < 2; ks++) {
                half8 kh = *(const half8*)(qh + krow + ks * 32 + fq * 8);
                acc = __builtin_amdgcn_mfma_f32_16x16x32_f16(qf0[ks], kh, acc, 0, 0, 0);
            }
            sc[kt] = acc;
        }
        float mx[4] = {-3e38f, -3e38f, -3e38f, -3e38f};
#pragma unroll
        for (int kt = 0; kt < KT; kt++) {
            bool valid = (kt * 16 + fr) < nk;
#pragma unroll
            for (int r = 0; r < 4; r++) {
                float s = sc[kt][r] * 0.125f;
                sc[kt][r] = s;
                if (valid) mx[r] = fmaxf(mx[r], s);
            }
        }
#pragma unroll
        for (int off = 1; off < 16; off <<= 1)
#pragma unroll
            for (int r = 0; r < 4; r++) mx[r] = fmaxf(mx[r], __shfl_xor(mx[r], off));
        float sum[4] = {0.f, 0.f, 0.f, 0.f};
#pragma unroll
        for (int kt = 0; kt < KT; kt++) {
            bool valid = (kt * 16 + fr) < nk;
#pragma unroll
            for (int r = 0; r < 4; r++) {
                float p = valid ? __expf(sc[kt][r] - mx[r]) : 0.f;
                sc[kt][r] = p;
                sum[r] += p;
            }
        }
#pragma unroll
        for (int off = 1; off < 16; off <<= 1)
#pragma unroll
            for (int r = 0; r < 4; r++) sum[r] += __shfl_xor(sum[r], off);
        float inv[4];
#pragma unroll
        for (int r = 0; r < 4; r++) inv[r] = 1.f / sum[r];
        unsigned short* Pw = PL + w * 16 * PSTR;
#pragma unroll
        for (int kt = 0; kt < KT; kt++) {
#pragma unroll
            for (int r = 0; r < 4; r++)
                Pw[(fq * 4 + r) * PSTR + kt * 16 + fr] = f2h(sc[kt][r] * inv[r]);
        }
        f32x4 o[4];
#pragma unroll
        for (int n = 0; n < 4; n++) o[n] = (f32x4)0.f;
#pragma unroll
        for (int ks = 0; ks < PVKT; ks++) {
            half8 pa = *(const half8*)(Pw + fr * PSTR + ks * 32 + fq * 8);
#pragma unroll
            for (int n = 0; n < 4; n++) {
                half8 vb = *(const half8*)(VT + (n * 16 + fr) * PSTR + ks * 32 + fq * 8);
                o[n] = __builtin_amdgcn_mfma_f32_16x16x32_f16(pa, vb, o[n], 0, 0, 0);
            }
        }
#pragma unroll
        for (int n = 0; n < 4; n++) {
#pragma unroll
            for (int r = 0; r < 4; r++) {
                int row = qt * 16 + fq * 4 + r;
                if (row < S) {
                    size_t oidx = ((size_t)b * S + row) * 768 + (size_t)h * 64 + n * 16 + fr;
                    oh[oidx] = f2h(o[n][r]);
                }
            }
        }
    }
}

// ---------------------------------------------------------------- prune machinery (fp16 in)
__global__ __launch_bounds__(256) void normsq_k(const unsigned short* __restrict__ x,
                                                float* __restrict__ norms)
{
    const unsigned short* xr = x + (size_t)blockIdx.x * 768;
    int t = threadIdx.x;
    float v0 = h2f(xr[t]), v1 = h2f(xr[t + 256]), v2 = h2f(xr[t + 512]);
    float ss = v0 * v0 + v1 * v1 + v2 * v2;
#pragma unroll
    for (int o = 32; o; o >>= 1) ss += __shfl_xor(ss, o);
    __shared__ float r1[4];
    if ((t & 63) == 0) r1[t >> 6] = ss;
    __syncthreads();
    if (t == 0) norms[blockIdx.x] = r1[0] + r1[1] + r1[2] + r1[3];
}

__global__ __launch_bounds__(256) void topk_k(const float* __restrict__ norms,
                                              int* __restrict__ idxmap, int* __restrict__ cnt)
{
    int b = blockIdx.x, t = threadIdx.x;
    __shared__ float n[NTOK];
    __shared__ unsigned char kp[NTOK];
    if (t < NTOK) n[t] = norms[b * NTOK + t];
    __syncthreads();
    if (t < NTOK) {
        float me = n[t];
        int rank = 0;
        for (int j = 0; j < NTOK; j++) rank += (n[j] > me) || (n[j] == me && j < t);
        kp[t] = (rank < 98) || (t == 0);
    }
    __syncthreads();
    if (t == 0) {
        int c = 0;
        for (int s = 0; s < NTOK; s++) if (kp[s]) idxmap[b * SL + c++] = s;
        cnt[b] = c;
        for (int j = c; j < SL; j++) idxmap[b * SL + j] = 0;
    }
}

__global__ __launch_bounds__(256) void gather_k(const unsigned short* __restrict__ x,
                                                const int* __restrict__ idxmap,
                                                const int* __restrict__ cnt,
                                                unsigned short* __restrict__ xl)
{
    int j = blockIdx.x, b = blockIdx.y;
    size_t dst = ((size_t)b * SL + j) * 768;
    if (j < cnt[b]) {
        int s = idxmap[b * SL + j];
        size_t src = ((size_t)b * NTOK + s) * 768;
        for (int d = threadIdx.x; d < 768; d += 256) xl[dst + d] = x[src + d];
    } else {
        for (int d = threadIdx.x; d < 768; d += 256) xl[dst + d] = 0;
    }
}

// ---------------------------------------------------------------- launch
extern "C" void kernel_launch(void* const* d_in, const int* in_sizes, int n_in,
                              void* d_out, int out_size, void* d_ws, size_t ws_size,
                              hipStream_t stream)
{
    const float* images  = (const float*)d_in[0];
    const float* patch_w = (const float*)d_in[1];
    const float* patch_b = (const float*)d_in[2];
    const float* cls_tok = (const float*)d_in[3];
    const float* pos_emb = (const float*)d_in[4];
    const float* ln1_g   = (const float*)d_in[5];
    const float* ln1_b   = (const float*)d_in[6];
    const float* qkv_w   = (const float*)d_in[7];
    const float* qkv_b   = (const float*)d_in[8];
    const float* proj_w  = (const float*)d_in[9];
    const float* proj_b  = (const float*)d_in[10];
    const float* ln2_g   = (const float*)d_in[11];
    const float* ln2_b   = (const float*)d_in[12];
    const float* fc1_w   = (const float*)d_in[13];
    const float* fc1_b   = (const float*)d_in[14];
    const float* fc2_w   = (const float*)d_in[15];
    const float* fc2_b   = (const float*)d_in[16];
    const float* norm_g  = (const float*)d_in[17];
    const float* norm_b  = (const float*)d_in[18];
    const float* head_w  = (const float*)d_in[19];
    const float* head_b  = (const float*)d_in[20];
    float* outp = (float*)d_out;

    char* W = (char*)d_ws;
    unsigned short* x16  = (unsigned short*)W;                   // 19,365,888
    unsigned short* hbh  = (unsigned short*)(W + 19365888);      // 19,365,888
    char* R = W + 38731776;                                      // 77,463,552 shared
    unsigned short* ph   = (unsigned short*)R;
    unsigned short* emb  = (unsigned short*)(R + 19365888);
    unsigned short* qkh  = (unsigned short*)R;
    unsigned short* ffh  = (unsigned short*)R;
    unsigned short* xl16 = (unsigned short*)(W + 116195328);
    unsigned short* wb4  = (unsigned short*)(W + 125927424);     // 4 layers x 14,155,776
    unsigned short* pwh  = (unsigned short*)(W + 182550528);
    unsigned short* hwb  = (unsigned short*)(W + 183730176);
    float* norms         = (float*)(W + 185303040);
    unsigned short* clsb = (unsigned short*)(W + 185353472);
    int* idxmap          = (int*)(W + 185451776);
    int* cnt             = (int*)(W + 185477120);

    const int LDS_EARLY = (64 * 232 + 4 * 16 * 232) * 2;   // 59,392
    const int LDS_LATE  = (64 * 136 + 4 * 16 * 136) * 2;   // 34,816
    const int LDS_WG    = 3 * 12288 * 2;                    // 73,728
    (void)hipFuncSetAttribute(reinterpret_cast<const void*>(&attn2_k<197, 13, 7, 232>),
                              hipFuncAttributeMaxDynamicSharedMemorySize, LDS_EARLY);
    (void)hipFuncSetAttribute(reinterpret_cast<const void*>(&attn2_k<99, 7, 4, 136>),
                              hipFuncAttributeMaxDynamicSharedMemorySize, LDS_LATE);
    (void)hipFuncSetAttribute(reinterpret_cast<const void*>(&wgemm_k<0>),
                              hipFuncAttributeMaxDynamicSharedMemorySize, LDS_WG);
    (void)hipFuncSetAttribute(reinterpret_cast<const void*>(&wgemm_k<1>),
                              hipFuncAttributeMaxDynamicSharedMemorySize, LDS_WG);

    // chunked grids: grid = 8 * nRloc * nC, nRloc = ceil(nR/8); 128-row tiles
    const int nR1 = 99, nRl1 = 13;     // M = 12608
    const int nRp = 98, nRlp = 13;     // patch M = 12544
    const int nR2 = 50, nRl2 = 7;      // M = 6336

    // ---- patch embed ----
    cvt_simple_k<<<576, 256, 0, stream>>>(patch_w, pwh, 147456);
    patch_extract2_k<<<dim3(196, NB), 256, 0, stream>>>(images, ph);
    mgemm_k<0, 1, 3><<<8 * nRlp * 6, 256, 0, stream>>>(ph, pwh, patch_b, nullptr,
        emb, nullptr, 12544, 768, 768, nRp, 6, nRlp);
    assemble_k<<<dim3(NTOK, NB), 256, 0, stream>>>(emb, cls_tok, pos_emb, x16);

    const int M1 = NB * NTOK;   // 12608
    for (int i = 0; i < 4; i++) {
        if (i == 0)
            cvt_layer4_k<<<4 * 6912, 256, 0, stream>>>(qkv_w, proj_w, fc1_w, fc2_w, 0, wb4);
        unsigned short* wbh = wb4 + (size_t)(i & 3) * 7077888;
        ln2_k<<<M1, 256, 0, stream>>>(x16, hbh, ln1_g + (size_t)i * 768, ln1_b + (size_t)i * 768, 768);
        wgemm_k<0><<<8 * nRl1 * 9, 256, LDS_WG, stream>>>(hbh, wbh,
            qkv_b + (size_t)i * 2304, qkh, M1, 2304, 768, nR1, 9, nRl1);
        attn2_k<197, 13, 7, 232><<<dim3(NHEAD, NB), 256, LDS_EARLY, stream>>>(qkh, hbh, nullptr);
        mgemm_k<2, 1, 3><<<8 * nRl1 * 6, 256, 0, stream>>>(hbh, wbh + 1769472,
            proj_b + (size_t)i * 768, x16, x16, nullptr, M1, 768, 768, nR1, 6, nRl1);
        ln2_k<<<M1, 256, 0, stream>>>(x16, hbh, ln2_g + (size_t)i * 768, ln2_b + (size_t)i * 768, 768);
        wgemm_k<1><<<8 * nRl1 * 12, 256, LDS_WG, stream>>>(hbh, wbh + 2359296,
            fc1_b + (size_t)i * 3072, ffh, M1, 3072, 768, nR1, 12, nRl1);
        mgemm_k<2, 1, 4><<<8 * nRl1 * 6, 256, 0, stream>>>(ffh, wbh + 4718592,
            fc2_b + (size_t)i * 768, x16, x16, nullptr, M1, 768, 3072, nR1, 6, nRl1);
    }

    // ---- prune + compact ----
    normsq_k<<<M1, 256, 0, stream>>>(x16, norms);
    topk_k<<<NB, 256, 0, stream>>>(norms, idxmap, cnt);
    gather_k<<<dim3(SL, NB), 256, 0, stream>>>(x16, idxmap, cnt, xl16);

    const int M2 = NB * SL;     // 6336
    for (int i = 4; i < 12; i++) {
        if (i == 4)
            cvt_layer4_k<<<4 * 6912, 256, 0, stream>>>(qkv_w, proj_w, fc1_w, fc2_w, 4, wb4);
        if (i == 8)
            cvt_layer4_k<<<4 * 6912, 256, 0, stream>>>(qkv_w, proj_w, fc1_w, fc2_w, 8, wb4);
        unsigned short* wbh = wb4 + (size_t)(i & 3) * 7077888;
        ln2_k<<<M2, 256, 0, stream>>>(xl16, hbh, ln1_g + (size_t)i * 768, ln1_b + (size_t)i * 768, 768);
        wgemm_k<0><<<8 * nRl2 * 9, 256, LDS_WG, stream>>>(hbh, wbh,
            qkv_b + (size_t)i * 2304, qkh, M2, 2304, 768, nR2, 9, nRl2);
        attn2_k<99, 7, 4, 136><<<dim3(NHEAD, NB), 256, LDS_LATE, stream>>>(qkh, hbh, cnt);
        mgemm_k<2, 1, 3><<<8 * nRl2 * 6, 256, 0, stream>>>(hbh, wbh + 1769472,
            proj_b + (size_t)i * 768, xl16, xl16, nullptr, M2, 768, 768, nR2, 6, nRl2);
        ln2_k<<<M2, 256, 0, stream>>>(xl16, hbh, ln2_g + (size_t)i * 768, ln2_b + (size_t)i * 768, 768);
        wgemm_k<1><<<8 * nRl2 * 12, 256, LDS_WG, stream>>>(hbh, wbh + 2359296,
            fc1_b + (size_t)i * 3072, ffh, M2, 3072, 768, nR2, 12, nRl2);
        mgemm_k<2, 1, 4><<<8 * nRl2 * 6, 256, 0, stream>>>(ffh, wbh + 4718592,
            fc2_b + (size_t)i * 768, xl16, xl16, nullptr, M2, 768, 3072, nR2, 6, nRl2);
    }

    // ---- final LN(CLS) + head ----
    ln2_k<<<NB, 256, 0, stream>>>(xl16, clsb, norm_g, norm_b, (size_t)SL * 768);
    cvt_simple_k<<<750, 256, 0, stream>>>(head_w, hwb, 192000);
    mgemm_k<0, 0, 0><<<8, 256, 0, stream>>>(clsb, hwb,
        head_b, nullptr, nullptr, outp, 64, 1000, 768, 1, 8, 1);
}

// Round 12
// 3733.311 us; speedup vs baseline: 1.0907x; 1.0907x over previous
//
#include <hip/hip_runtime.h>
#include <cstdint>
#include <cstddef>

// ViT-B/16 + token pruning. Round 12: R10 GEMM structure (proven best) +
// (1) 1-wave vectorized LN/normsq/gather (us4 loads, wave-only reduce),
// (2) GELU via A&S 7.1.26 erf poly (|eps|<=1.5e-7, rcp+exp+5fma),
// (3) s_setprio around attention MFMA clusters (T5, independent-wave regime).

#define NTOK 197
#define NB 64
#define NHEAD 12
#define SL 99

typedef __attribute__((ext_vector_type(8))) _Float16 half8;
typedef __attribute__((ext_vector_type(4))) float f32x4;
typedef __attribute__((ext_vector_type(4))) unsigned short us4;

#define DEV static __device__ __forceinline__

DEV unsigned short f2h(float f) {
    union { _Float16 h; unsigned short u; } v;
    v.h = (_Float16)f;
    return v.u;
}
DEV float h2f(unsigned short u) {
    union { _Float16 h; unsigned short u; } v;
    v.u = u;
    return (float)v.h;
}

DEV void gload16(const void* g, void* l) {
    __builtin_amdgcn_global_load_lds((const __attribute__((address_space(1))) unsigned int*)g,
                                     (__attribute__((address_space(3))) unsigned int*)l, 16, 0, 0);
}

// GELU with Abramowitz-Stegun 7.1.26 erf (|eps| <= 1.5e-7, effectively exact vs fp16 noise)
DEV float gelu_f(float v) {
    float x = v * 0.70710678118654752f;
    float ax = fabsf(x);
    float t = __builtin_amdgcn_rcpf(fmaf(0.3275911f, ax, 1.0f));
    float poly = fmaf(fmaf(fmaf(fmaf(1.061405429f, t, -1.453152027f), t,
                               1.421413741f), t, -0.284496736f), t, 0.254829592f) * t;
    float erf_ax = 1.0f - poly * __expf(-x * x);
    float er = (x < 0.f) ? -erf_ax : erf_ax;
    return 0.5f * v * (1.0f + er);
}

// ---------------------------------------------------------------- weight conversion (4 layers / launch)
__global__ __launch_bounds__(256) void cvt_layer4_k(const float* __restrict__ qw,
                                                    const float* __restrict__ pw,
                                                    const float* __restrict__ f1,
                                                    const float* __restrict__ f2,
                                                    int i0,
                                                    unsigned short* __restrict__ dst)
{
    int l = blockIdx.x / 6912;
    int b2 = blockIdx.x % 6912;
    int li = i0 + l;
    size_t t = (size_t)b2 * 256 + threadIdx.x;
    size_t e = t * 4;
    const float* src; size_t loc;
    if (e < 1769472)      { src = qw + (size_t)li * 1769472; loc = e; }
    else if (e < 2359296) { src = pw + (size_t)li * 589824;  loc = e - 1769472; }
    else if (e < 4718592) { src = f1 + (size_t)li * 2359296; loc = e - 2359296; }
    else                  { src = f2 + (size_t)li * 2359296; loc = e - 4718592; }
    float4 v = *(const float4*)(src + loc);
    us4 hi; hi.x = f2h(v.x); hi.y = f2h(v.y); hi.z = f2h(v.z); hi.w = f2h(v.w);
    *(us4*)(dst + (size_t)l * 7077888 + e) = hi;
}

__global__ __launch_bounds__(256) void cvt_simple_k(const float* __restrict__ src,
                                                    unsigned short* __restrict__ dh, int n4)
{
    int t = blockIdx.x * 256 + threadIdx.x;
    if (t >= n4) return;
    size_t e = (size_t)t * 4;
    float4 v = *(const float4*)(src + e);
    us4 hi; hi.x = f2h(v.x); hi.y = f2h(v.y); hi.z = f2h(v.z); hi.w = f2h(v.w);
    *(us4*)(dh + e) = hi;
}

// ---------------------------------------------------------------- patch extract
__global__ __launch_bounds__(256) void patch_extract2_k(const float* __restrict__ img,
                                                        unsigned short* __restrict__ ph)
{
    int pi = blockIdx.x, b = blockIdx.y;
    int gy = pi / 14, gx = pi % 14;
    size_t obase = ((size_t)b * 196 + pi) * 768;
    for (int f = threadIdx.x; f < 768; f += 256) {
        int c = f >> 8, py = (f >> 4) & 15, px = f & 15;
        float v = img[(((size_t)b * 3 + c) * 224 + gy * 16 + py) * 224 + gx * 16 + px];
        ph[obase + f] = f2h(v);
    }
}

__global__ __launch_bounds__(256) void assemble_k(const unsigned short* __restrict__ emb,
                                                  const float* __restrict__ cls,
                                                  const float* __restrict__ pos,
                                                  unsigned short* __restrict__ x)
{
    int s = blockIdx.x, b = blockIdx.y;
    size_t xo = ((size_t)b * NTOK + s) * 768;
    for (int d = threadIdx.x; d < 768; d += 256) {
        float v = (s == 0) ? cls[d] : h2f(emb[((size_t)b * 196 + (s - 1)) * 768 + d]);
        x[xo + d] = f2h(v + pos[(size_t)s * 768 + d]);
    }
}

// ---------------------------------------------------------------- 1-wave vectorized layernorm (fp16->fp16)
// 64 threads, each lane handles 12 contiguous elements (3x us4 loads).
__global__ __launch_bounds__(64) void lnw_k(const unsigned short* __restrict__ in,
                                            unsigned short* __restrict__ outh,
                                            const float* __restrict__ g,
                                            const float* __restrict__ bt, size_t ldin)
{
    const unsigned short* xr = in + (size_t)blockIdx.x * ldin;
    size_t ob = (size_t)blockIdx.x * 768;
    const int t = threadIdx.x;            // 0..63
    const int e0 = t * 12;

    us4 a = *(const us4*)(xr + e0);
    us4 b = *(const us4*)(xr + e0 + 4);
    us4 c = *(const us4*)(xr + e0 + 8);
    float v[12];
    v[0] = h2f(a.x); v[1] = h2f(a.y); v[2]  = h2f(a.z); v[3]  = h2f(a.w);
    v[4] = h2f(b.x); v[5] = h2f(b.y); v[6]  = h2f(b.z); v[7]  = h2f(b.w);
    v[8] = h2f(c.x); v[9] = h2f(c.y); v[10] = h2f(c.z); v[11] = h2f(c.w);

    float s = 0.f;
#pragma unroll
    for (int e = 0; e < 12; e++) s += v[e];
#pragma unroll
    for (int o = 32; o; o >>= 1) s += __shfl_xor(s, o);
    float mean = s * (1.f / 768.f);
    float ss = 0.f;
#pragma unroll
    for (int e = 0; e < 12; e++) { float d = v[e] - mean; ss += d * d; }
#pragma unroll
    for (int o = 32; o; o >>= 1) ss += __shfl_xor(ss, o);
    float inv = rsqrtf(ss * (1.f / 768.f) + 1e-6f);

    float4 g0 = *(const float4*)(g + e0),  g1 = *(const float4*)(g + e0 + 4),  g2 = *(const float4*)(g + e0 + 8);
    float4 b0 = *(const float4*)(bt + e0), b1 = *(const float4*)(bt + e0 + 4), b2 = *(const float4*)(bt + e0 + 8);
    float gg[12] = {g0.x,g0.y,g0.z,g0.w, g1.x,g1.y,g1.z,g1.w, g2.x,g2.y,g2.z,g2.w};
    float bb[12] = {b0.x,b0.y,b0.z,b0.w, b1.x,b1.y,b1.z,b1.w, b2.x,b2.y,b2.z,b2.w};
    unsigned short o16[12];
#pragma unroll
    for (int e = 0; e < 12; e++) o16[e] = f2h((v[e] - mean) * inv * gg[e] + bb[e]);
    us4 oa = {o16[0], o16[1], o16[2],  o16[3]};
    us4 obv = {o16[4], o16[5], o16[6],  o16[7]};
    us4 oc = {o16[8], o16[9], o16[10], o16[11]};
    *(us4*)(outh + ob + e0)     = oa;
    *(us4*)(outh + ob + e0 + 4) = obv;
    *(us4*)(outh + ob + e0 + 8) = oc;
}

// ---------------------------------------------------------------- 128x128 fp16 GEMM, ring-3 (R10)
// EPI: 0 none, 1 GELU, 2 +res(fp16). OS: 0 fp32 out, 1 fp16 out.
// MAP: 0 linear; 3 chunked rows-fastest; 4 chunked cols-fastest.
template<int EPI, int OS, int MAP>
__global__ __launch_bounds__(256) void mgemm_k(const unsigned short* __restrict__ Ah,
                                               const unsigned short* __restrict__ Wh,
                                               const float* __restrict__ bias,
                                               const unsigned short* __restrict__ res,
                                               unsigned short* __restrict__ Chi,
                                               float* __restrict__ Cf,
                                               int M, int N, int K, int nR, int nC, int nRloc)
{
    __shared__ unsigned short lds[3 * 8192];

    int rt, ct;
    {
        int bid = blockIdx.x;
        if (MAP == 0) { rt = bid % nR; ct = bid / nR; }
        else {
            int xcd = bid & 7, u = bid >> 3, rl, c;
            if (MAP == 3) { rl = u % nRloc; c = u / nRloc; }
            else          { c = u % nC;     rl = u / nC;   }
            rt = xcd * nRloc + rl; ct = c;
            if (rt >= nR) return;
        }
    }
    const int row0 = rt << 7, col0 = ct << 7;
    const int tid = threadIdx.x;
    const int w = tid >> 6, lane = tid & 63;
    const int wr = w >> 1, wc = w & 1;
    const int srow = lane >> 2;
    const int schunk = ((lane & 3) ^ ((srow >> 1) & 3)) << 3;
    const int fr = lane & 15, fq = lane >> 4;
    const int rchunk = (fq ^ ((fr >> 1) & 3)) << 3;

    f32x4 acc[4][4];
#pragma unroll
    for (int m = 0; m < 4; m++)
#pragma unroll
        for (int n = 0; n < 4; n++) acc[m][n] = (f32x4)0.f;

    const int nk = K >> 5;

    auto stage = [&](int t, int slot) {
        const int k0 = t << 5;
        unsigned short* Ad = lds + slot * 8192;
        unsigned short* Bd = Ad + 4096;
#pragma unroll
        for (int i = 0; i < 2; i++) {
            int r = i * 64 + w * 16 + srow;
            int ga = row0 + r; if (ga > M - 1) ga = M - 1;
            int gb = col0 + r; if (gb > N - 1) gb = N - 1;
            gload16(Ah + (size_t)ga * K + k0 + schunk, Ad + i * 2048 + w * 512);
            gload16(Wh + (size_t)gb * K + k0 + schunk, Bd + i * 2048 + w * 512);
        }
    };

    stage(0, 0);
    stage(1, 1);
    int slot = 0, slot2 = 2;
    for (int t = 0; t < nk; ++t) {
        if (t + 1 < nk) asm volatile("s_waitcnt vmcnt(4)" ::: "memory");
        else            asm volatile("s_waitcnt vmcnt(0)" ::: "memory");
        __builtin_amdgcn_s_barrier();
        if (t + 2 < nk) stage(t + 2, slot2);
        const unsigned short* Ab = lds + slot * 8192;
        const unsigned short* Bb = Ab + 4096;
        half8 a[4], bb[4];
#pragma unroll
        for (int m = 0; m < 4; m++)
            a[m] = *(const half8*)(Ab + (wr * 64 + m * 16 + fr) * 32 + rchunk);
#pragma unroll
        for (int n = 0; n < 4; n++)
            bb[n] = *(const half8*)(Bb + (wc * 64 + n * 16 + fr) * 32 + rchunk);
#pragma unroll
        for (int m = 0; m < 4; m++)
#pragma unroll
            for (int n = 0; n < 4; n++)
                acc[m][n] = __builtin_amdgcn_mfma_f32_16x16x32_f16(a[m], bb[n], acc[m][n], 0, 0, 0);
        slot = (slot == 2) ? 0 : slot + 1;
        slot2 = (slot2 == 2) ? 0 : slot2 + 1;
    }

#pragma unroll
    for (int m = 0; m < 4; m++) {
#pragma unroll
        for (int n = 0; n < 4; n++) {
            int col = col0 + wc * 64 + n * 16 + fr;
#pragma unroll
            for (int r = 0; r < 4; r++) {
                int row = row0 + wr * 64 + m * 16 + fq * 4 + r;
                if (row < M && col < N) {
                    float v = acc[m][n][r] + bias[col];
                    size_t o = (size_t)row * N + col;
                    if (EPI == 2) v += h2f(res[o]);
                    if (EPI == 1) v = gelu_f(v);
                    if (OS == 0) Cf[o] = v;
                    else Chi[o] = f2h(v);
                }
            }
        }
    }
}

// ---------------------------------------------------------------- fused MFMA attention (fp16, +setprio)
template<int S, int KT, int PVKT, int PSTR>
__global__ __launch_bounds__(256) void attn2_k(const unsigned short* __restrict__ qh,
                                               unsigned short* __restrict__ oh,
                                               const int* __restrict__ cntp)
{
    constexpr int PVK = PVKT * 32;
    constexpr int QT = (S + 15) / 16;
    extern __shared__ unsigned short sh[];
    unsigned short* VT = sh;
    unsigned short* PL = sh + 64 * PSTR;

    const int h = blockIdx.x, b = blockIdx.y;
    const int tid = threadIdx.x, w = tid >> 6, lane = tid & 63;
    const int nk = cntp ? cntp[b] : S;
    const size_t qbase = (size_t)b * S * 2304 + (size_t)h * 64;
    const int fr = lane & 15, fq = lane >> 4;

    for (int j0 = 0; j0 < S; j0 += 32) {
        int j = j0 + (tid >> 3);
        int d8 = (tid & 7) * 8;
        if (j < S) {
            size_t src = qbase + (size_t)j * 2304 + 1536 + d8;
            us4 v0 = *(const us4*)(qh + src);
            us4 v1 = *(const us4*)(qh + src + 4);
            VT[(d8 + 0) * PSTR + j] = v0.x; VT[(d8 + 1) * PSTR + j] = v0.y;
            VT[(d8 + 2) * PSTR + j] = v0.z; VT[(d8 + 3) * PSTR + j] = v0.w;
            VT[(d8 + 4) * PSTR + j] = v1.x; VT[(d8 + 5) * PSTR + j] = v1.y;
            VT[(d8 + 6) * PSTR + j] = v1.z; VT[(d8 + 7) * PSTR + j] = v1.w;
        }
    }
    for (int idx = tid; idx < 64 * (PVK - S); idx += 256) {
        int d = idx / (PVK - S), j = S + idx % (PVK - S);
        VT[d * PSTR + j] = 0;
    }
    {
        unsigned short* Pw = PL + w * 16 * PSTR;
        for (int idx = lane; idx < 16 * (PVK - 16 * KT); idx += 64) {
            int rr = idx / (PVK - 16 * KT), cc = 16 * KT + idx % (PVK - 16 * KT);
            Pw[rr * PSTR + cc] = 0;
        }
    }
    __syncthreads();

    for (int qt = w; qt < QT; qt += 4) {
        int qr = qt * 16 + fr; int qrc = qr < S ? qr : S - 1;
        const size_t qrow = qbase + (size_t)qrc * 2304;
        half8 qf0[2];
#pragma unroll
        for (int ks = 0; ks < 2; ks++)
            qf0[ks] = *(const half8*)(qh + qrow + ks * 32 + fq * 8);
        f32x4 sc[KT];
        __builtin_amdgcn_s_setprio(1);
#pragma unroll
        for (int kt = 0; kt < KT; kt++) {
            int ky = kt * 16 + fr; int kyc = ky < S ? ky : S - 1;
            const size_t krow = qbase + (size_t)kyc * 2304 + 768;
            f32x4 acc = (f32x4)0.f;
#pragma unroll
            for (int ks = 0; ks < 2; ks++) {
                half8 kh = *(const half8*)(qh + krow + ks * 32 + fq * 8);
                acc = __builtin_amdgcn_mfma_f32_16x16x32_f16(qf0[ks], kh, acc, 0, 0, 0);
            }
            sc[kt] = acc;
        }
        __builtin_amdgcn_s_setprio(0);
        float mx[4] = {-3e38f, -3e38f, -3e38f, -3e38f};
#pragma unroll
        for (int kt = 0; kt < KT; kt++) {
            bool valid = (kt * 16 + fr) < nk;
#pragma unroll
            for (int r = 0; r < 4; r++) {
                float s = sc[kt][r] * 0.125f;
                sc[kt][r] = s;
                if (valid) mx[r] = fmaxf(mx[r], s);
            }
        }
#pragma unroll
        for (int off = 1; off < 16; off <<= 1)
#pragma unroll
            for (int r = 0; r < 4; r++) mx[r] = fmaxf(mx[r], __shfl_xor(mx[r], off));
        float sum[4] = {0.f, 0.f, 0.f, 0.f};
#pragma unroll
        for (int kt = 0; kt < KT; kt++) {
            bool valid = (kt * 16 + fr) < nk;
#pragma unroll
            for (int r = 0; r < 4; r++) {
                float p = valid ? __expf(sc[kt][r] - mx[r]) : 0.f;
                sc[kt][r] = p;
                sum[r] += p;
            }
        }
#pragma unroll
        for (int off = 1; off < 16; off <<= 1)
#pragma unroll
            for (int r = 0; r < 4; r++) sum[r] += __shfl_xor(sum[r], off);
        float inv[4];
#pragma unroll
        for (int r = 0; r < 4; r++) inv[r] = 1.f / sum[r];
        unsigned short* Pw = PL + w * 16 * PSTR;
#pragma unroll
        for (int kt = 0; kt < KT; kt++) {
#pragma unroll
            for (int r = 0; r < 4; r++)
                Pw[(fq * 4 + r) * PSTR + kt * 16 + fr] = f2h(sc[kt][r] * inv[r]);
        }
        f32x4 o[4];
#pragma unroll
        for (int n = 0; n < 4; n++) o[n] = (f32x4)0.f;
        __builtin_amdgcn_s_setprio(1);
#pragma unroll
        for (int ks = 0; ks < PVKT; ks++) {
            half8 pa = *(const half8*)(Pw + fr * PSTR + ks * 32 + fq * 8);
#pragma unroll
            for (int n = 0; n < 4; n++) {
                half8 vb = *(const half8*)(VT + (n * 16 + fr) * PSTR + ks * 32 + fq * 8);
                o[n] = __builtin_amdgcn_mfma_f32_16x16x32_f16(pa, vb, o[n], 0, 0, 0);
            }
        }
        __builtin_amdgcn_s_setprio(0);
#pragma unroll
        for (int n = 0; n < 4; n++) {
#pragma unroll
            for (int r = 0; r < 4; r++) {
                int row = qt * 16 + fq * 4 + r;
                if (row < S) {
                    size_t oidx = ((size_t)b * S + row) * 768 + (size_t)h * 64 + n * 16 + fr;
                    oh[oidx] = f2h(o[n][r]);
                }
            }
        }
    }
}

// ---------------------------------------------------------------- prune machinery (1-wave, vectorized)
__global__ __launch_bounds__(64) void normsq_k(const unsigned short* __restrict__ x,
                                               float* __restrict__ norms)
{
    const unsigned short* xr = x + (size_t)blockIdx.x * 768;
    const int t = threadIdx.x;
    const int e0 = t * 12;
    us4 a = *(const us4*)(xr + e0);
    us4 b = *(const us4*)(xr + e0 + 4);
    us4 c = *(const us4*)(xr + e0 + 8);
    float ss = 0.f;
    float v;
    v = h2f(a.x); ss += v * v; v = h2f(a.y); ss += v * v;
    v = h2f(a.z); ss += v * v; v = h2f(a.w); ss += v * v;
    v = h2f(b.x); ss += v * v; v = h2f(b.y); ss += v * v;
    v = h2f(b.z); ss += v * v; v = h2f(b.w); ss += v * v;
    v = h2f(c.x); ss += v * v; v = h2f(c.y); ss += v * v;
    v = h2f(c.z); ss += v * v; v = h2f(c.w); ss += v * v;
#pragma unroll
    for (int o = 32; o; o >>= 1) ss += __shfl_xor(ss, o);
    if (t == 0) norms[blockIdx.x] = ss;
}

__global__ __launch_bounds__(256) void topk_k(const float* __restrict__ norms,
                                              int* __restrict__ idxmap, int* __restrict__ cnt)
{
    int b = blockIdx.x, t = threadIdx.x;
    __shared__ float n[NTOK];
    __shared__ unsigned char kp[NTOK];
    if (t < NTOK) n[t] = norms[b * NTOK + t];
    __syncthreads();
    if (t < NTOK) {
        float me = n[t];
        int rank = 0;
        for (int j = 0; j < NTOK; j++) rank += (n[j] > me) || (n[j] == me && j < t);
        kp[t] = (rank < 98) || (t == 0);
    }
    __syncthreads();
    if (t == 0) {
        int c = 0;
        for (int s = 0; s < NTOK; s++) if (kp[s]) idxmap[b * SL + c++] = s;
        cnt[b] = c;
        for (int j = c; j < SL; j++) idxmap[b * SL + j] = 0;
    }
}

__global__ __launch_bounds__(64) void gather_k(const unsigned short* __restrict__ x,
                                               const int* __restrict__ idxmap,
                                               const int* __restrict__ cnt,
                                               unsigned short* __restrict__ xl)
{
    int j = blockIdx.x, b = blockIdx.y;
    size_t dst = ((size_t)b * SL + j) * 768;
    const int t = threadIdx.x;
    const int e0 = t * 12;
    if (j < cnt[b]) {
        int s = idxmap[b * SL + j];
        size_t src = ((size_t)b * NTOK + s) * 768;
        *(us4*)(xl + dst + e0)     = *(const us4*)(x + src + e0);
        *(us4*)(xl + dst + e0 + 4) = *(const us4*)(x + src + e0 + 4);
        *(us4*)(xl + dst + e0 + 8) = *(const us4*)(x + src + e0 + 8);
    } else {
        us4 z = {0, 0, 0, 0};
        *(us4*)(xl + dst + e0)     = z;
        *(us4*)(xl + dst + e0 + 4) = z;
        *(us4*)(xl + dst + e0 + 8) = z;
    }
}

// ---------------------------------------------------------------- launch
extern "C" void kernel_launch(void* const* d_in, const int* in_sizes, int n_in,
                              void* d_out, int out_size, void* d_ws, size_t ws_size,
                              hipStream_t stream)
{
    const float* images  = (const float*)d_in[0];
    const float* patch_w = (const float*)d_in[1];
    const float* patch_b = (const float*)d_in[2];
    const float* cls_tok = (const float*)d_in[3];
    const float* pos_emb = (const float*)d_in[4];
    const float* ln1_g   = (const float*)d_in[5];
    const float* ln1_b   = (const float*)d_in[6];
    const float* qkv_w   = (const float*)d_in[7];
    const float* qkv_b   = (const float*)d_in[8];
    const float* proj_w  = (const float*)d_in[9];
    const float* proj_b  = (const float*)d_in[10];
    const float* ln2_g   = (const float*)d_in[11];
    const float* ln2_b   = (const float*)d_in[12];
    const float* fc1_w   = (const float*)d_in[13];
    const float* fc1_b   = (const float*)d_in[14];
    const float* fc2_w   = (const float*)d_in[15];
    const float* fc2_b   = (const float*)d_in[16];
    const float* norm_g  = (const float*)d_in[17];
    const float* norm_b  = (const float*)d_in[18];
    const float* head_w  = (const float*)d_in[19];
    const float* head_b  = (const float*)d_in[20];
    float* outp = (float*)d_out;

    char* W = (char*)d_ws;
    unsigned short* x16  = (unsigned short*)W;                   // 19,365,888
    unsigned short* hbh  = (unsigned short*)(W + 19365888);      // 19,365,888
    char* R = W + 38731776;                                      // 77,463,552 shared
    unsigned short* ph   = (unsigned short*)R;
    unsigned short* emb  = (unsigned short*)(R + 19365888);
    unsigned short* qkh  = (unsigned short*)R;
    unsigned short* ffh  = (unsigned short*)R;
    unsigned short* xl16 = (unsigned short*)(W + 116195328);
    unsigned short* wb4  = (unsigned short*)(W + 125927424);     // 4 layers x 14,155,776
    unsigned short* pwh  = (unsigned short*)(W + 182550528);
    unsigned short* hwb  = (unsigned short*)(W + 183730176);
    float* norms         = (float*)(W + 185303040);
    unsigned short* clsb = (unsigned short*)(W + 185353472);
    int* idxmap          = (int*)(W + 185451776);
    int* cnt             = (int*)(W + 185477120);

    const int LDS_EARLY = (64 * 232 + 4 * 16 * 232) * 2;   // 59,392
    const int LDS_LATE  = (64 * 136 + 4 * 16 * 136) * 2;   // 34,816
    (void)hipFuncSetAttribute(reinterpret_cast<const void*>(&attn2_k<197, 13, 7, 232>),
                              hipFuncAttributeMaxDynamicSharedMemorySize, LDS_EARLY);
    (void)hipFuncSetAttribute(reinterpret_cast<const void*>(&attn2_k<99, 7, 4, 136>),
                              hipFuncAttributeMaxDynamicSharedMemorySize, LDS_LATE);

    // chunked grids: grid = 8 * nRloc * nC, nRloc = ceil(nR/8); 128-row tiles
    const int nR1 = 99, nRl1 = 13;     // M = 12608
    const int nRp = 98, nRlp = 13;     // patch M = 12544
    const int nR2 = 50, nRl2 = 7;      // M = 6336

    // ---- patch embed ----
    cvt_simple_k<<<576, 256, 0, stream>>>(patch_w, pwh, 147456);
    patch_extract2_k<<<dim3(196, NB), 256, 0, stream>>>(images, ph);
    mgemm_k<0, 1, 3><<<8 * nRlp * 6, 256, 0, stream>>>(ph, pwh, patch_b, nullptr,
        emb, nullptr, 12544, 768, 768, nRp, 6, nRlp);
    assemble_k<<<dim3(NTOK, NB), 256, 0, stream>>>(emb, cls_tok, pos_emb, x16);

    const int M1 = NB * NTOK;   // 12608
    for (int i = 0; i < 4; i++) {
        if (i == 0)
            cvt_layer4_k<<<4 * 6912, 256, 0, stream>>>(qkv_w, proj_w, fc1_w, fc2_w, 0, wb4);
        unsigned short* wbh = wb4 + (size_t)(i & 3) * 7077888;
        lnw_k<<<M1, 64, 0, stream>>>(x16, hbh, ln1_g + (size_t)i * 768, ln1_b + (size_t)i * 768, 768);
        mgemm_k<0, 1, 3><<<8 * nRl1 * 18, 256, 0, stream>>>(hbh, wbh,
            qkv_b + (size_t)i * 2304, nullptr, qkh, nullptr, M1, 2304, 768, nR1, 18, nRl1);
        attn2_k<197, 13, 7, 232><<<dim3(NHEAD, NB), 256, LDS_EARLY, stream>>>(qkh, hbh, nullptr);
        mgemm_k<2, 1, 3><<<8 * nRl1 * 6, 256, 0, stream>>>(hbh, wbh + 1769472,
            proj_b + (size_t)i * 768, x16, x16, nullptr, M1, 768, 768, nR1, 6, nRl1);
        lnw_k<<<M1, 64, 0, stream>>>(x16, hbh, ln2_g + (size_t)i * 768, ln2_b + (size_t)i * 768, 768);
        mgemm_k<1, 1, 3><<<8 * nRl1 * 24, 256, 0, stream>>>(hbh, wbh + 2359296,
            fc1_b + (size_t)i * 3072, nullptr, ffh, nullptr, M1, 3072, 768, nR1, 24, nRl1);
        mgemm_k<2, 1, 4><<<8 * nRl1 * 6, 256, 0, stream>>>(ffh, wbh + 4718592,
            fc2_b + (size_t)i * 768, x16, x16, nullptr, M1, 768, 3072, nR1, 6, nRl1);
    }

    // ---- prune + compact ----
    normsq_k<<<M1, 64, 0, stream>>>(x16, norms);
    topk_k<<<NB, 256, 0, stream>>>(norms, idxmap, cnt);
    gather_k<<<dim3(SL, NB), 64, 0, stream>>>(x16, idxmap, cnt, xl16);

    const int M2 = NB * SL;     // 6336
    for (int i = 4; i < 12; i++) {
        if (i == 4)
            cvt_layer4_k<<<4 * 6912, 256, 0, stream>>>(qkv_w, proj_w, fc1_w, fc2_w, 4, wb4);
        if (i == 8)
            cvt_layer4_k<<<4 * 6912, 256, 0, stream>>>(qkv_w, proj_w, fc1_w, fc2_w, 8, wb4);
        unsigned short* wbh = wb4 + (size_t)(i & 3) * 7077888;
        lnw_k<<<M2, 64, 0, stream>>>(xl16, hbh, ln1_g + (size_t)i * 768, ln1_b + (size_t)i * 768, 768);
        mgemm_k<0, 1, 3><<<8 * nRl2 * 18, 256, 0, stream>>>(hbh, wbh,
            qkv_b + (size_t)i * 2304, nullptr, qkh, nullptr, M2, 2304, 768, nR2, 18, nRl2);
        attn2_k<99, 7, 4, 136><<<dim3(NHEAD, NB), 256, LDS_LATE, stream>>>(qkh, hbh, cnt);
        mgemm_k<2, 1, 3><<<8 * nRl2 * 6, 256, 0, stream>>>(hbh, wbh + 1769472,
            proj_b + (size_t)i * 768, xl16, xl16, nullptr, M2, 768, 768, nR2, 6, nRl2);
        lnw_k<<<M2, 64, 0, stream>>>(xl16, hbh, ln2_g + (size_t)i * 768, ln2_b + (size_t)i * 768, 768);
        mgemm_k<1, 1, 3><<<8 * nRl2 * 24, 256, 0, stream>>>(hbh, wbh + 2359296,
            fc1_b + (size_t)i * 3072, nullptr, ffh, nullptr, M2, 3072, 768, nR2, 24, nRl2);
        mgemm_k<2, 1, 4><<<8 * nRl2 * 6, 256, 0, stream>>>(ffh, wbh + 4718592,
            fc2_b + (size_t)i * 768, xl16, xl16, nullptr, M2, 768, 3072, nR2, 6, nRl2);
    }

    // ---- final LN(CLS) + head ----
    lnw_k<<<NB, 64, 0, stream>>>(xl16, clsb, norm_g, norm_b, (size_t)SL * 768);
    cvt_simple_k<<<750, 256, 0, stream>>>(head_w, hwb, 192000);
    mgemm_k<0, 0, 0><<<8, 256, 0, stream>>>(clsb, hwb,
        head_b, nullptr, nullptr, outp, 64, 1000, 768, 1, 8, 1);
}